// Round 4
// baseline (1015.261 us; speedup 1.0000x reference)
//
#include <hip/hip_runtime.h>
#include <hip/hip_cooperative_groups.h>

namespace cg = cooperative_groups;

#define NV 20000          // vertices
#define NE 4096           // hyperedges
#define FT 128            // features
#define NW_E 128          // u32 words per packed vertex row  (E/32)
#define NW_V 625          // u32 words per packedT edge row   (N/32), 625*32 == 20000 exactly
#define NVP 20032         // padded vertex count for dv partials
#define SPLITK 8          // mm1 split-K factor (8 * 64 e-tiles = 512 blocks exactly)
#define CHUNKK 2560       // ceil(20000 / 8 / 64) * 64

typedef __attribute__((ext_vector_type(8))) short short8v;   // 8 bf16 (4 VGPRs) — MFMA A/B frag
typedef __attribute__((ext_vector_type(4))) float float4v;   // 4 fp32 — MFMA C/D frag

__device__ __forceinline__ unsigned short f2bf(float f) {    // fp32 -> bf16 RNE
    unsigned u = __float_as_uint(f);
    u += 0x7FFFu + ((u >> 16) & 1u);
    return (unsigned short)(u >> 16);
}
// LDS tile: rows of 64 bf16 (128B), 16B chunks XOR-swizzled by row to kill bank conflicts
__device__ __forceinline__ int lds_off(int r, int chunk) {
    return r * 128 + ((chunk ^ (r & 7)) << 4);
}
// build one 16B LUT entry: byte value -> 8 bf16 in {0.0, 1.0}
__device__ __forceinline__ uint4 lut_entry(int t) {
    uint4 e;
    e.x = ((t & 1) ? 0x3F80u : 0u) | ((t & 2) ? 0x3F800000u : 0u);
    e.y = ((t & 4) ? 0x3F80u : 0u) | ((t & 8) ? 0x3F800000u : 0u);
    e.z = ((t & 16) ? 0x3F80u : 0u) | ((t & 32) ? 0x3F800000u : 0u);
    e.w = ((t & 64) ? 0x3F80u : 0u) | ((t & 128) ? 0x3F800000u : 0u);
    return e;
}

// One cooperative kernel, 512 blocks x 256 threads (2 blocks/CU co-resident:
// LDS 28KB/block, <=256 VGPR via launch_bounds). Phases separated by grid.sync().
__global__ __launch_bounds__(256, 2) void k_mega(
    const int* __restrict__ H, const float* __restrict__ X,
    const float* __restrict__ W, const float* __restrict__ bias,
    float* __restrict__ out,
    unsigned* __restrict__ packed, unsigned* __restrict__ packedT,
    int* __restrict__ dvp, unsigned short* __restrict__ Ybf,
    float* __restrict__ P, float* __restrict__ Tt,
    unsigned short* __restrict__ Ubf, float* __restrict__ dv,
    float* __restrict__ de) {

    __shared__ __align__(16) unsigned char sA[16384];   // 128 rows x 128 B
    __shared__ __align__(16) unsigned char sB[8192];    //  64 rows x 128 B
    __shared__ __align__(16) uint4 slut[256];

    cg::grid_group grid = cg::this_grid();
    int t = threadIdx.x;
    int wave = t >> 6, lane = t & 63;
    int r0 = lane & 15, q = lane >> 4;

    slut[t] = lut_entry(t);

    // ---------------- phase 1: pack H + bit-transpose + dv partial counts ----------------
    {
        int* cl = (int*)sA;
        for (int v = blockIdx.x; v < 626; v += 512) {
            int g = v >> 1, h = v & 1;
            int w0 = h * 64 + wave * 16;
            int n = g * 64 + lane;
            bool valid = n < NV;
            const uint4* base = reinterpret_cast<const uint4*>(H) + (size_t)n * (NE / 4);

            if (t < 64) cl[t] = 0;
            __syncthreads();

            int cnt = 0;
            int nw = g * 2 + (lane >> 5);
            for (int it = 0; it < 16; ++it) {
                int w = w0 + it;
                unsigned m = 0;
                if (valid) {
                    const uint4* p = base + w * 8;
#pragma unroll
                    for (int i = 0; i < 8; ++i) {
                        uint4 vv = p[i];
                        m |= (vv.x ? 1u : 0u) << (i * 4 + 0);
                        m |= (vv.y ? 1u : 0u) << (i * 4 + 1);
                        m |= (vv.z ? 1u : 0u) << (i * 4 + 2);
                        m |= (vv.w ? 1u : 0u) << (i * 4 + 3);
                    }
                    packed[(size_t)n * NW_E + w] = m;
                }
                cnt += __popc(m);
                unsigned my = 0;
#pragma unroll
                for (int j = 0; j < 32; ++j) {
                    unsigned long long bm = __ballot(((m >> j) & 1u) != 0);
                    unsigned part = (lane < 32) ? (unsigned)bm : (unsigned)(bm >> 32);
                    if ((lane & 31) == j) my = part;
                }
                int e = w * 32 + (lane & 31);
                if (nw < NW_V) packedT[(size_t)e * NW_V + nw] = my;
            }
            atomicAdd(&cl[lane], cnt);
            __syncthreads();
            if (t < 64) dvp[h * NVP + g * 64 + t] = cl[t];
            __syncthreads();
        }
    }
    grid.sync();

    // ---------------- phase 2: edge degree | dv finalize | Ybf transpose ----------------
    for (int v = blockIdx.x; v < 2353; v += 512) {
        if (v < 1024) {
            int e = v * 4 + wave;
            const unsigned* row = packedT + (size_t)e * NW_V;
            int c = 0;
            for (int i = lane; i < NW_V; i += 64) c += __popc(row[i]);
            for (int o = 32; o > 0; o >>= 1) c += __shfl_down(c, o, 64);
            if (lane == 0) de[e] = c > 0 ? 1.0f / (float)c : 1.0f;
        } else if (v < 1024 + 79) {
            int i = (v - 1024) * 256 + t;
            if (i < NV) {
                int d = dvp[i] + dvp[NVP + i];
                dv[i] = d > 0 ? 1.0f / sqrtf((float)d) : 1.0f;
            }
        } else {
            int b2 = v - 1103;
            int f = t & 127;
            int nb = (b2 * 2 + (t >> 7)) * 8;   // 1250 virt * 2 * 8 == 20000 exactly
            unsigned short h[8];
#pragma unroll
            for (int i = 0; i < 8; ++i) {
                int n = nb + i;
                int d = dvp[n] + dvp[NVP + n];
                float s = d > 0 ? 1.0f / sqrtf((float)d) : 1.0f;
                h[i] = f2bf(X[(size_t)n * FT + f] * s);
            }
            uint4 u;
            u.x = (unsigned)h[0] | ((unsigned)h[1] << 16);
            u.y = (unsigned)h[2] | ((unsigned)h[3] << 16);
            u.z = (unsigned)h[4] | ((unsigned)h[5] << 16);
            u.w = (unsigned)h[6] | ((unsigned)h[7] << 16);
            *reinterpret_cast<uint4*>(Ybf + (size_t)f * NV + nb) = u;
        }
    }
    grid.sync();

    // ---------------- phase 3: mm1 partials, 128f x 64e tiles, split-K 8 ----------------
    {
        int et = blockIdx.x & 63, kp = blockIdx.x >> 6;
        int e0 = et * 64;
        int kbeg = kp * CHUNKK;

        float4v acc[4][2];
#pragma unroll
        for (int i = 0; i < 4; ++i)
#pragma unroll
            for (int j = 0; j < 2; ++j)
#pragma unroll
                for (int r = 0; r < 4; ++r) acc[i][j][r] = 0.0f;

        int fA = t & 127;
        int chbA = (t >> 7) * 4;
        const unsigned short* arow = Ybf + (size_t)fA * NV;
        int rB = t & 63, wsel = (t >> 6) & 1, bsel = t >> 7;
        const unsigned* brow = packedT + (size_t)(e0 + rB) * NW_V;

        int wm0 = (wave & 1) * 64, wc0 = (wave >> 1) * 32;

        for (int it = 0; it < CHUNKK / 64; ++it) {
            int k0 = kbeg + it * 64;
            // stage A: 128 f-rows x 64 n (bf16)
#pragma unroll
            for (int c = 0; c < 4; ++c) {
                int ch = chbA + c;
                int n = k0 + ch * 8;
                uint4 v = {0, 0, 0, 0};
                if (n < NV) v = *reinterpret_cast<const uint4*>(arow + n);
                *reinterpret_cast<uint4*>(sA + lds_off(fA, ch)) = v;
            }
            // stage B: 64 e-rows x 64 n from bits via LUT (2 bytes/thread)
            {
                int nw = (k0 >> 5) + wsel;
                unsigned wv = (nw < NW_V) ? brow[nw] : 0u;
#pragma unroll
                for (int c = 0; c < 2; ++c) {
                    int byte = bsel * 2 + c;
                    uint4 u = slut[(wv >> (byte * 8)) & 0xFF];
                    *reinterpret_cast<uint4*>(sB + lds_off(rB, wsel * 4 + byte)) = u;
                }
            }
            __syncthreads();
#pragma unroll
            for (int ks = 0; ks < 2; ++ks) {
                short8v a[4], bb[2];
#pragma unroll
                for (int mi = 0; mi < 4; ++mi)
                    a[mi] = *reinterpret_cast<const short8v*>(sA + lds_off(wm0 + mi * 16 + r0, ks * 4 + q));
#pragma unroll
                for (int ci = 0; ci < 2; ++ci)
                    bb[ci] = *reinterpret_cast<const short8v*>(sB + lds_off(wc0 + ci * 16 + r0, ks * 4 + q));
#pragma unroll
                for (int mi = 0; mi < 4; ++mi)
#pragma unroll
                    for (int ci = 0; ci < 2; ++ci)
                        acc[mi][ci] = __builtin_amdgcn_mfma_f32_16x16x32_bf16(a[mi], bb[ci], acc[mi][ci], 0, 0, 0);
            }
            __syncthreads();
        }
        float* Pp = P + (size_t)kp * (128 * 4096);
#pragma unroll
        for (int mi = 0; mi < 4; ++mi)
#pragma unroll
            for (int ci = 0; ci < 2; ++ci) {
                int f = wm0 + mi * 16 + q * 4;
                int e = e0 + wc0 + ci * 16 + r0;
#pragma unroll
                for (int r = 0; r < 4; ++r)
                    Pp[(size_t)(f + r) * 4096 + e] = acc[mi][ci][r];
            }
    }
    grid.sync();

    // ---------------- phase 4: reduce split-K partials ----------------
    {
        int i = blockIdx.x * 256 + t;   // 131072 float4 total
        const float4v* Pv = (const float4v*)P;
        float4v a = Pv[i];
#pragma unroll
        for (int p = 1; p < SPLITK; ++p) a += Pv[(size_t)p * 131072 + i];
        ((float4v*)Tt)[i] = a;
    }
    grid.sync();

    // ---------------- phase 5: Ubf[g][e] = bf16( de[e] * sum_f W[f][g] * Tt[f][e] ) ----------------
    {
        int bx = blockIdx.x & 63, by = blockIdx.x >> 6;
        int e = bx * 64 + (t & 63);
        int g0 = by * 16 + (t >> 6) * 4;
        float a0 = 0, a1 = 0, a2 = 0, a3 = 0;
        for (int f = 0; f < 128; ++f) {
            float tv = Tt[(size_t)f * 4096 + e];
            float4 wv = *reinterpret_cast<const float4*>(W + f * 128 + g0);
            a0 += tv * wv.x; a1 += tv * wv.y; a2 += tv * wv.z; a3 += tv * wv.w;
        }
        float d = de[e];
        Ubf[(size_t)(g0 + 0) * 4096 + e] = f2bf(a0 * d);
        Ubf[(size_t)(g0 + 1) * 4096 + e] = f2bf(a1 * d);
        Ubf[(size_t)(g0 + 2) * 4096 + e] = f2bf(a2 * d);
        Ubf[(size_t)(g0 + 3) * 4096 + e] = f2bf(a3 * d);
    }
    grid.sync();

    // ---------------- phase 6: mm2 out[n][g] = dv[n]*sum_e H[n][e]*Ubf[g][e] + bias[g] ----------------
    for (int v = blockIdx.x; v < 628; v += 512) {
        int mt = v >> 2, qg = v & 3;
        int n0 = mt * 128, g0 = qg * 32;

        float4v acc[4];
#pragma unroll
        for (int i = 0; i < 4; ++i)
#pragma unroll
            for (int r = 0; r < 4; ++r) acc[i][r] = 0.0f;

        int nA = t & 127, hA = t >> 7;
        int rB = t & 31, cB = t >> 5;
        const unsigned short* brow = Ubf + (size_t)(g0 + rB) * 4096;

        int wm0 = (wave & 1) * 64, wc0 = (wave >> 1) * 16;
        __syncthreads();

        for (int k0 = 0; k0 < 4096; k0 += 64) {
            {
                unsigned wv = (n0 + nA < NV) ? packed[(size_t)(n0 + nA) * NW_E + (k0 >> 5) + hA] : 0u;
#pragma unroll
                for (int c = 0; c < 4; ++c) {
                    uint4 u = slut[(wv >> (c * 8)) & 0xFF];
                    *reinterpret_cast<uint4*>(sA + lds_off(nA, hA * 4 + c)) = u;
                }
            }
            {
                uint4 v2 = *reinterpret_cast<const uint4*>(brow + k0 + cB * 8);
                *reinterpret_cast<uint4*>(sB + lds_off(rB, cB)) = v2;
            }
            __syncthreads();
#pragma unroll
            for (int ks = 0; ks < 2; ++ks) {
                short8v a[4], bb;
#pragma unroll
                for (int mi = 0; mi < 4; ++mi)
                    a[mi] = *reinterpret_cast<const short8v*>(sA + lds_off(wm0 + mi * 16 + r0, ks * 4 + q));
                bb = *reinterpret_cast<const short8v*>(sB + lds_off(wc0 + r0, ks * 4 + q));
#pragma unroll
                for (int mi = 0; mi < 4; ++mi)
                    acc[mi] = __builtin_amdgcn_mfma_f32_16x16x32_bf16(a[mi], bb, acc[mi], 0, 0, 0);
            }
            __syncthreads();
        }
        {
            int g = g0 + wc0 + r0;
            float bg = bias[g];
#pragma unroll
            for (int mi = 0; mi < 4; ++mi) {
#pragma unroll
                for (int r = 0; r < 4; ++r) {
                    int n = n0 + wm0 + mi * 16 + q * 4 + r;
                    if (n < NV) out[(size_t)n * 128 + g] = dv[n] * acc[mi][r] + bg;
                }
            }
        }
    }
}

extern "C" void kernel_launch(void* const* d_in, const int* in_sizes, int n_in,
                              void* d_out, int out_size, void* d_ws, size_t ws_size,
                              hipStream_t stream) {
    const int*   H    = (const int*)d_in[1];
    const float* X    = (const float*)d_in[0];
    const float* W    = (const float*)d_in[2];
    const float* bias = (const float*)d_in[3];
    float* out = (float*)d_out;

    char* ws = (char*)d_ws;
    size_t off = 0;
    auto alloc = [&](size_t sz) { char* p = ws + off; off += (sz + 255) & ~(size_t)255; return p; };
    unsigned*       packed  = (unsigned*)alloc((size_t)NV * NW_E * 4);      // 10.24 MB
    unsigned*       packedT = (unsigned*)alloc((size_t)NE * NW_V * 4);      // 10.24 MB
    unsigned short* Ybf     = (unsigned short*)alloc((size_t)FT * NV * 2);  //  5.12 MB
    float*          Tt      = (float*)alloc((size_t)FT * NE * 4);           //  2.10 MB
    unsigned short* Ubf     = (unsigned short*)alloc((size_t)FT * NE * 2);  //  1.05 MB
    float*          dv      = (float*)alloc((size_t)NV * 4);
    float*          de      = (float*)alloc((size_t)NE * 4);
    int*            dvp     = (int*)alloc((size_t)2 * NVP * 4);             //  0.16 MB
    float*          P1      = (float*)alloc((size_t)SPLITK * FT * NE * 4);  // 16.8 MB

    void* args[] = {(void*)&H, (void*)&X, (void*)&W, (void*)&bias, (void*)&out,
                    (void*)&packed, (void*)&packedT, (void*)&dvp, (void*)&Ybf,
                    (void*)&P1, (void*)&Tt, (void*)&Ubf, (void*)&dv, (void*)&de};
    hipLaunchCooperativeKernel(reinterpret_cast<void*>(k_mega), dim3(512), dim3(256),
                               args, 0, stream);
}

// Round 5
// 590.707 us; speedup vs baseline: 1.7187x; 1.7187x over previous
//
#include <hip/hip_runtime.h>

#define NV 20000          // vertices
#define NE 4096           // hyperedges
#define FT 128            // features
#define NW_E 128          // u32 words per packed vertex row  (E/32)
#define NW_V 625          // real u32 words per packedT edge row (N/32), 625*32 == 20000
#define PT_STRIDE 632     // padded packedT row stride (prefetch may read past word 625)
#define NKC 313           // padded n-chunks of 64 (313*64 = 20032)

typedef __attribute__((ext_vector_type(8))) short short8v;   // 8 bf16 — MFMA A/B frag
typedef __attribute__((ext_vector_type(4))) float float4v;   // 4 fp32 — MFMA C/D frag

__device__ __forceinline__ unsigned short f2bf(float f) {    // fp32 -> bf16 RNE
    unsigned u = __float_as_uint(f);
    u += 0x7FFFu + ((u >> 16) & 1u);
    return (unsigned short)(u >> 16);
}
// LDS tile: rows of 64 bf16 (128B), 16B chunks XOR-swizzled by row
__device__ __forceinline__ int lds_off(int r, int chunk) {
    return r * 128 + ((chunk ^ (r & 7)) << 4);
}
// 16B LUT entry: byte -> 8 bf16 in {0.0, 1.0}
__device__ __forceinline__ uint4 lut_entry(int t) {
    uint4 e;
    e.x = ((t & 1) ? 0x3F80u : 0u) | ((t & 2) ? 0x3F800000u : 0u);
    e.y = ((t & 4) ? 0x3F80u : 0u) | ((t & 8) ? 0x3F800000u : 0u);
    e.z = ((t & 16) ? 0x3F80u : 0u) | ((t & 32) ? 0x3F800000u : 0u);
    e.w = ((t & 64) ? 0x3F80u : 0u) | ((t & 128) ? 0x3F800000u : 0u);
    return e;
}

// ---------------- 1. pack H -> bits, COALESCED: wave = half row ----------------
// block = 2 rows (4 waves). Lane reads 128B contiguous; lane's 32 ints = 1 packed word.
__global__ __launch_bounds__(256) void k_pack(const int* __restrict__ H,
                                              unsigned* __restrict__ packed,
                                              float* __restrict__ dv) {
    __shared__ int cl[4];
    int t = threadIdx.x, wave = t >> 6, lane = t & 63;
    int row = blockIdx.x * 2 + (wave >> 1);
    int half = wave & 1;
    const uint4* base = reinterpret_cast<const uint4*>(H) + (size_t)row * 1024 + half * 512 + lane * 8;
    unsigned m = 0;
#pragma unroll
    for (int i = 0; i < 8; ++i) {
        uint4 v = base[i];
        m |= (v.x ? 1u : 0u) << (i * 4 + 0);
        m |= (v.y ? 1u : 0u) << (i * 4 + 1);
        m |= (v.z ? 1u : 0u) << (i * 4 + 2);
        m |= (v.w ? 1u : 0u) << (i * 4 + 3);
    }
    packed[(size_t)row * NW_E + half * 64 + lane] = m;
    int c = __popc(m);
    for (int o = 32; o > 0; o >>= 1) c += __shfl_down(c, o, 64);
    if (lane == 0) cl[wave] = c;
    __syncthreads();
    if (t < 2) {
        int d = cl[t * 2] + cl[t * 2 + 1];
        dv[blockIdx.x * 2 + t] = d > 0 ? 1.0f / sqrtf((float)d) : 1.0f;
    }
}

// ---------------- 2. bit-transpose packed -> packedT via ballot ----------------
__global__ __launch_bounds__(256) void k_btrans(const unsigned* __restrict__ packed,
                                                unsigned* __restrict__ packedT) {
    int lane = threadIdx.x & 63;
    int w = threadIdx.x >> 6;
    int ew = blockIdx.y * 4 + w;
    int n = blockIdx.x * 64 + lane;
    unsigned wv = (n < NV) ? packed[(size_t)n * NW_E + ew] : 0u;
    unsigned my = 0;
#pragma unroll
    for (int j = 0; j < 32; ++j) {
        unsigned long long m = __ballot(((wv >> j) & 1u) != 0);
        unsigned part = (lane < 32) ? (unsigned)m : (unsigned)(m >> 32);
        if ((lane & 31) == j) my = part;
    }
    int nw = blockIdx.x * 2 + (lane >> 5);
    int e = ew * 32 + (lane & 31);
    if (nw <= 625) packedT[(size_t)e * PT_STRIDE + nw] = my;
}

// ---------------- 3. edge degree | At tiled build ----------------
// blocks [0,1024): edge degree. [1024,2274): At[kc][f][j]=bf16(dv*X) tiled. [2274]: zero pad.
__global__ __launch_bounds__(256) void k_mid(const unsigned* __restrict__ packedT,
                                             const float* __restrict__ X,
                                             const float* __restrict__ dv,
                                             float* __restrict__ de,
                                             unsigned short* __restrict__ At) {
    int b = blockIdx.x, t = threadIdx.x;
    int wave = t >> 6, lane = t & 63;
    if (b < 1024) {
        int e = b * 4 + wave;
        const unsigned* row = packedT + (size_t)e * PT_STRIDE;
        int c = 0;
        for (int i = lane; i < NW_V; i += 64) c += __popc(row[i]);
        for (int o = 32; o > 0; o >>= 1) c += __shfl_down(c, o, 64);
        if (lane == 0) de[e] = c > 0 ? 1.0f / (float)c : 1.0f;
    } else if (b < 2274) {
        int b2 = b - 1024;
        int f = t & 127;
        int nb = (b2 * 2 + (t >> 7)) * 8;   // 1250 virt * 16 n == 20000 exactly
        unsigned short h[8];
#pragma unroll
        for (int i = 0; i < 8; ++i) {
            int n = nb + i;
            h[i] = f2bf(X[(size_t)n * FT + f] * dv[n]);
        }
        uint4 u;
        u.x = (unsigned)h[0] | ((unsigned)h[1] << 16);
        u.y = (unsigned)h[2] | ((unsigned)h[3] << 16);
        u.z = (unsigned)h[4] | ((unsigned)h[5] << 16);
        u.w = (unsigned)h[6] | ((unsigned)h[7] << 16);
        int kc = nb >> 6;
        *reinterpret_cast<uint4*>(At + (size_t)kc * 8192 + f * 64 + (nb & 63)) = u;
    } else {
        // zero pad chunk kc=312, j in [32,64): n = 20000..20031
        int f = t & 127;
        uint4 z = {0, 0, 0, 0};
        *reinterpret_cast<uint4*>(At + (size_t)312 * 8192 + f * 64 + 32 + (t >> 7) * 8) = z;
        *reinterpret_cast<uint4*>(At + (size_t)312 * 8192 + f * 64 + 48 + (t >> 7) * 8) = z;
    }
}

// ---------------- 4. mm1: P[kp][f][e] = sum_n At[f][n] * H[n][e], split-K ----------------
// A-staging fully coalesced from tiled At; B bits with double-buffered uint4 prefetch.
__global__ __launch_bounds__(256, 2) void k_mm1(const unsigned short* __restrict__ At,
                                                const unsigned* __restrict__ packedT,
                                                float* __restrict__ P, int chunkK) {
    __shared__ __align__(16) unsigned char sA[16384];   // 128 f x 64 n bf16
    __shared__ __align__(16) unsigned char sB[16384];   // 128 e x 64 n bf16
    __shared__ __align__(16) uint4 slut[256];
    int t = threadIdx.x;
    slut[t] = lut_entry(t);

    int et = blockIdx.x & 31, kp = blockIdx.x >> 5;
    int e0 = et * 128;
    int kbeg = kp * chunkK;
    int kend = kbeg + chunkK; if (kend > NKC * 64) kend = NKC * 64;
    int iters = (kend - kbeg) >> 6; if (iters < 0) iters = 0;

    float4v acc[4][4];
#pragma unroll
    for (int i = 0; i < 4; ++i)
#pragma unroll
        for (int j = 0; j < 4; ++j)
#pragma unroll
            for (int r = 0; r < 4; ++r) acc[i][j][r] = 0.0f;

    int wave = t >> 6, lane = t & 63;
    int wm0 = (wave & 1) * 64, wc0 = (wave >> 1) * 64;
    int r0 = lane & 15, q = lane >> 4;

    // B prefetch: thread t<128 owns e-row t; uint4 = 4 words = 2 iters
    const unsigned* brow = packedT + (size_t)(e0 + (t & 127)) * PT_STRIDE + (kbeg >> 5);
    uint4 bw, bw2;
    if (t < 128) bw = *reinterpret_cast<const uint4*>(brow);
    __syncthreads();   // LUT ready

    for (int it = 0; it < iters; ++it) {
        int kc = (kbeg >> 6) + it;
        // stage A: 16KB contiguous slab, 256 thr x 4 x 16B, per-instr coalesced
        const uint4* slab = reinterpret_cast<const uint4*>(At + (size_t)kc * 8192);
#pragma unroll
        for (int c = 0; c < 4; ++c) {
            int idx = c * 256 + t;
            uint4 v = slab[idx];
            *reinterpret_cast<uint4*>(sA + lds_off(idx >> 3, idx & 7)) = v;
        }
        // stage B: 2 words/row via LUT; prefetch next pair at even iters
        if (t < 128) {
            unsigned w0, w1;
            if (!(it & 1)) {
                bw2 = *reinterpret_cast<const uint4*>(brow + 2 * it + 4);  // pad keeps in-bounds
                w0 = bw.x; w1 = bw.y;
            } else {
                w0 = bw.z; w1 = bw.w;
            }
            int rB = t;
#pragma unroll
            for (int c = 0; c < 4; ++c)
                *reinterpret_cast<uint4*>(sB + lds_off(rB, c)) = slut[(w0 >> (c * 8)) & 0xFF];
#pragma unroll
            for (int c = 0; c < 4; ++c)
                *reinterpret_cast<uint4*>(sB + lds_off(rB, 4 + c)) = slut[(w1 >> (c * 8)) & 0xFF];
            if (it & 1) bw = bw2;
        }
        __syncthreads();
#pragma unroll
        for (int ks = 0; ks < 2; ++ks) {
            short8v a[4], bb[4];
#pragma unroll
            for (int mi = 0; mi < 4; ++mi)
                a[mi] = *reinterpret_cast<const short8v*>(sA + lds_off(wm0 + mi * 16 + r0, ks * 4 + q));
#pragma unroll
            for (int ci = 0; ci < 4; ++ci)
                bb[ci] = *reinterpret_cast<const short8v*>(sB + lds_off(wc0 + ci * 16 + r0, ks * 4 + q));
#pragma unroll
            for (int mi = 0; mi < 4; ++mi)
#pragma unroll
                for (int ci = 0; ci < 4; ++ci)
                    acc[mi][ci] = __builtin_amdgcn_mfma_f32_16x16x32_bf16(a[mi], bb[ci], acc[mi][ci], 0, 0, 0);
        }
        __syncthreads();
    }
    float* Pp = P + (size_t)kp * (128 * 4096);
#pragma unroll
    for (int mi = 0; mi < 4; ++mi)
#pragma unroll
        for (int ci = 0; ci < 4; ++ci) {
            int f = wm0 + mi * 16 + q * 4;
            int e = e0 + wc0 + ci * 16 + r0;
#pragma unroll
            for (int r = 0; r < 4; ++r)
                Pp[(size_t)(f + r) * 4096 + e] = acc[mi][ci][r];
        }
}

// ---------------- 5. reduce split-K partials ----------------
__global__ __launch_bounds__(256) void k_reduce(const float4v* __restrict__ P,
                                                float4v* __restrict__ Tt, int S) {
    int i = blockIdx.x * 256 + threadIdx.x;   // 131072 float4 total
    float4v a = P[i];
    for (int p = 1; p < S; ++p) a += P[(size_t)p * 131072 + i];
    Tt[i] = a;
}

// ---------------- 6. Ut[ec][g][j] = bf16( de * (Tt^T W)^T ), tiled for mm2 ----------------
__global__ __launch_bounds__(256) void k_ut(const float* __restrict__ Tt,
                                            const float* __restrict__ W,
                                            const float* __restrict__ de,
                                            unsigned short* __restrict__ Ut) {
    int t = threadIdx.x;
    int bx = blockIdx.x;
    int e = bx * 64 + (t & 63);
    int g0 = blockIdx.y * 16 + (t >> 6) * 4;
    float a0 = 0, a1 = 0, a2 = 0, a3 = 0;
    for (int f = 0; f < 128; ++f) {
        float tv = Tt[(size_t)f * 4096 + e];
        float4 wv = *reinterpret_cast<const float4*>(W + f * 128 + g0);
        a0 += tv * wv.x; a1 += tv * wv.y; a2 += tv * wv.z; a3 += tv * wv.w;
    }
    float d = de[e];
    int j = t & 63;
    Ut[(size_t)bx * 8192 + (g0 + 0) * 64 + j] = f2bf(a0 * d);
    Ut[(size_t)bx * 8192 + (g0 + 1) * 64 + j] = f2bf(a1 * d);
    Ut[(size_t)bx * 8192 + (g0 + 2) * 64 + j] = f2bf(a2 * d);
    Ut[(size_t)bx * 8192 + (g0 + 3) * 64 + j] = f2bf(a3 * d);
}

// ---------------- 7. mm2: out[n][g] = dv[n]*sum_e H[n][e]*U[g][e] + bias[g] ----------------
// A bits: t<128 owns n-row, double-buffered uint4 prefetch. B: contiguous tiled Ut.
__global__ __launch_bounds__(256, 4) void k_mm2(const unsigned* __restrict__ packed,
                                                const unsigned short* __restrict__ Ut,
                                                const float* __restrict__ dv,
                                                const float* __restrict__ bias,
                                                float* __restrict__ out) {
    __shared__ __align__(16) unsigned char sA[16384];   // 128 n x 64 e bf16
    __shared__ __align__(16) unsigned char sB[4096];    //  32 g x 64 e bf16
    __shared__ __align__(16) uint4 slut[256];
    int t = threadIdx.x;
    slut[t] = lut_entry(t);

    int mt = blockIdx.x >> 2, qg = blockIdx.x & 3;
    int n0 = mt * 128, g0 = qg * 32;

    float4v acc[4];
#pragma unroll
    for (int i = 0; i < 4; ++i)
#pragma unroll
        for (int r = 0; r < 4; ++r) acc[i][r] = 0.0f;

    int wave = t >> 6, lane = t & 63;
    int wm0 = (wave & 1) * 64, wc0 = (wave >> 1) * 16;
    int r0 = lane & 15, q = lane >> 4;

    const unsigned* arow = packed + (size_t)(n0 + (t & 127)) * NW_E;
    const unsigned short* bbase = Ut + (size_t)qg * 2048;
    int t2 = t - 128;
    uint4 aw, aw2;
    if (t < 128) aw = *reinterpret_cast<const uint4*>(arow);
    __syncthreads();   // LUT ready

    for (int it = 0; it < 64; ++it) {
        if (t < 128) {
            unsigned w0, w1;
            if (!(it & 1)) {
                aw2 = *reinterpret_cast<const uint4*>(arow + 2 * it + 4);  // may over-read, never consumed
                w0 = aw.x; w1 = aw.y;
            } else {
                w0 = aw.z; w1 = aw.w;
            }
            int rA = t;
#pragma unroll
            for (int c = 0; c < 4; ++c)
                *reinterpret_cast<uint4*>(sA + lds_off(rA, c)) = slut[(w0 >> (c * 8)) & 0xFF];
#pragma unroll
            for (int c = 0; c < 4; ++c)
                *reinterpret_cast<uint4*>(sA + lds_off(rA, 4 + c)) = slut[(w1 >> (c * 8)) & 0xFF];
            if (it & 1) aw = aw2;
        } else {
            // B: 4KB contiguous (32 g-rows x 64 e), 128 thr x 2 x 16B
            const uint4* src = reinterpret_cast<const uint4*>(bbase + (size_t)it * 8192);
#pragma unroll
            for (int c = 0; c < 2; ++c) {
                int idx = t2 * 2 + c;               // 16B unit: g = idx>>3, ch = idx&7... (idx*8 elems)
                uint4 v = src[idx];
                *reinterpret_cast<uint4*>(sB + lds_off(idx >> 3, idx & 7)) = v;
            }
        }
        __syncthreads();
#pragma unroll
        for (int ks = 0; ks < 2; ++ks) {
            short8v a[4], bb;
#pragma unroll
            for (int mi = 0; mi < 4; ++mi)
                a[mi] = *reinterpret_cast<const short8v*>(sA + lds_off(wm0 + mi * 16 + r0, ks * 4 + q));
            bb = *reinterpret_cast<const short8v*>(sB + lds_off(wc0 + r0, ks * 4 + q));
#pragma unroll
            for (int mi = 0; mi < 4; ++mi)
                acc[mi] = __builtin_amdgcn_mfma_f32_16x16x32_bf16(a[mi], bb, acc[mi], 0, 0, 0);
        }
        __syncthreads();
    }
    {
        int g = g0 + wc0 + r0;
        float bg = bias[g];
#pragma unroll
        for (int mi = 0; mi < 4; ++mi) {
#pragma unroll
            for (int r = 0; r < 4; ++r) {
                int n = n0 + wm0 + mi * 16 + q * 4 + r;
                if (n < NV) out[(size_t)n * 128 + g] = dv[n] * acc[mi][r] + bg;
            }
        }
    }
}

extern "C" void kernel_launch(void* const* d_in, const int* in_sizes, int n_in,
                              void* d_out, int out_size, void* d_ws, size_t ws_size,
                              hipStream_t stream) {
    const float* X    = (const float*)d_in[0];
    const int*   H    = (const int*)d_in[1];
    const float* W    = (const float*)d_in[2];
    const float* bias = (const float*)d_in[3];
    float* out = (float*)d_out;

    char* ws = (char*)d_ws;
    size_t off = 0;
    auto alloc = [&](size_t sz) { char* p = ws + off; off += (sz + 255) & ~(size_t)255; return p; };
    unsigned*       packed  = (unsigned*)alloc((size_t)NV * NW_E * 4);          // 10.24 MB
    unsigned*       packedT = (unsigned*)alloc((size_t)NE * PT_STRIDE * 4);     // 10.35 MB
    unsigned short* At      = (unsigned short*)alloc((size_t)NKC * 8192 * 2);   //  5.13 MB
    float*          Tt      = (float*)alloc((size_t)FT * NE * 4);               //  2.10 MB
    unsigned short* Ut      = (unsigned short*)alloc((size_t)FT * NE * 2);      //  1.05 MB
    float*          dv      = (float*)alloc((size_t)NV * 4);
    float*          de      = (float*)alloc((size_t)NE * 4);
    size_t fixed = off;

    long long avail = (long long)ws_size - (long long)fixed;
    int S = (int)(avail / (128LL * 4096 * 4));
    if (S > 16) S = 16;
    if (S < 1) S = 1;
    float* P1 = (float*)(ws + fixed);
    int chunkK = ((NKC * 64 + S * 64 - 1) / (S * 64)) * 64;

    k_pack  <<<NV / 2, 256, 0, stream>>>(H, packed, dv);
    k_btrans<<<dim3(313, 32), 256, 0, stream>>>(packed, packedT);
    k_mid   <<<2275, 256, 0, stream>>>(packedT, X, dv, de, At);
    k_mm1   <<<32 * S, 256, 0, stream>>>(At, packedT, P1, chunkK);
    k_reduce<<<512, 256, 0, stream>>>((const float4v*)P1, (float4v*)Tt, S);
    k_ut    <<<dim3(64, 8), 256, 0, stream>>>(Tt, W, de, Ut);
    k_mm2   <<<628, 256, 0, stream>>>(packed, Ut, dv, bias, out);
}